// Round 15
// baseline (311.126 us; speedup 1.0000x reference)
//
#include <hip/hip_runtime.h>

// Chamfer forward: dist0[i] = min_j ||pc0[i]-pc1[j]||^2 ; out = mean(dist0[dist0<=2])
// N = M = 65536 i.i.d. N(0,1)^3 points, fp32.
// Spatial grid G=64 (h=0.125), counting sort, two-phase query (R14: 157us).
// ROUND 15: hierarchical tail. pending_kernel was #1 (57us, VALUBusy 2.8%): deep
// queries expanded FINE rings to r~12 = ~180 serial dependent ends[] loads. Now
// phase 2 runs on a COARSE grid (G2=16, h2=0.5): rings 1..3 max (r=4 head always
// terminates: best<=2.25 -> exact, else masked), ~4 serial segment batches.
// Coarse build fused into existing kernels (count/scan_mid/scatter): no new launches.

constexpr int   NPTS  = 65536;
constexpr int   G     = 64;
constexpr int   NC    = G * G * G;   // 262144 cells
constexpr float H     = 0.125f;
constexpr float ORG   = -4.0f;
constexpr float INVH  = 8.0f;
constexpr int   G2    = 16;          // coarse grid (phase 2)
constexpr int   NC2   = G2 * G2 * G2;// 4096 cells
constexpr float H2    = 0.5f;
constexpr float INVH2 = 2.0f;
constexpr int   BLOCK = 256;
constexpr int   PBLOCKS = 256;       // pending kernel grid (fixed; done-counter)
constexpr int   SB    = 128;         // scan blocks per array
constexpr int   CHUNK = NC / SB;     // 2048 counts per scan block (2/thread)

__device__ __forceinline__ int cellOf(float x) {
  int c = (int)floorf((x - ORG) * INVH);
  return min(max(c, 0), G - 1);
}
__device__ __forceinline__ int cellOf2(float x) {
  int c = (int)floorf((x - ORG) * INVH2);
  return min(max(c, 0), G2 - 1);
}

__global__ __launch_bounds__(BLOCK) void count_kernel(
    const float* __restrict__ pc0, const float* __restrict__ pc1,
    unsigned* __restrict__ counts0, unsigned* __restrict__ counts1,
    unsigned* __restrict__ counts2) {
  const int gid = blockIdx.x * BLOCK + threadIdx.x;
  if (gid < NPTS) {   // pc1: fine + coarse histograms
    const float x = pc1[3 * gid], y = pc1[3 * gid + 1], z = pc1[3 * gid + 2];
    atomicAdd(&counts1[(cellOf(z) * G + cellOf(y)) * G + cellOf(x)], 1u);
    atomicAdd(&counts2[(cellOf2(z) * G2 + cellOf2(y)) * G2 + cellOf2(x)], 1u);
  } else {            // pc0: fine only
    const int i = gid - NPTS;
    const float x = pc0[3 * i], y = pc0[3 * i + 1], z = pc0[3 * i + 2];
    atomicAdd(&counts0[(cellOf(z) * G + cellOf(y)) * G + cellOf(x)], 1u);
  }
}

// Phase A: per-block partial sums. grid = (SB, 2); y=0 -> counts1, y=1 -> counts0.
__global__ __launch_bounds__(1024) void scan_partial_kernel(
    const unsigned* __restrict__ counts0, const unsigned* __restrict__ counts1,
    unsigned* __restrict__ partials) {
  const unsigned* counts = blockIdx.y ? counts0 : counts1;
  const int base = blockIdx.x * CHUNK + threadIdx.x * 2;
  unsigned sum = counts[base] + counts[base + 1];
  for (int o = 32; o; o >>= 1) sum += __shfl_down(sum, o, 64);
  __shared__ unsigned ws[16];
  if ((threadIdx.x & 63) == 0) ws[threadIdx.x >> 6] = sum;
  __syncthreads();
  if (threadIdx.x == 0) {
    unsigned t = 0;
    for (int w = 0; w < 16; ++w) t += ws[w];
    partials[blockIdx.y * SB + blockIdx.x] = t;
  }
}

// Phase B (1 block, 1024 thr): scan the 2x128 partials AND the coarse histogram.
__global__ __launch_bounds__(1024) void scan_mid_kernel(
    unsigned* __restrict__ partials,
    const unsigned* __restrict__ counts2, unsigned* __restrict__ cur2) {
  __shared__ unsigned wt[4];
  __shared__ unsigned wt2[16];
  const int tid = threadIdx.x;
  // part 1: tids 0..255 scan the two 128-entry partial arrays
  unsigned v = 0, inc = 0; int g = 0, li = 0;
  if (tid < 256) {
    g = tid >> 7; li = tid & 127;
    v = partials[g * SB + li];
    inc = v;
    for (int o = 1; o < 64; o <<= 1) {
      const unsigned t = __shfl_up(inc, o, 64);
      if ((tid & 63) >= o) inc += t;
    }
    if ((tid & 63) == 63) wt[tid >> 6] = inc;
  }
  __syncthreads();
  if (tid < 256) {
    const unsigned woff = ((tid >> 6) & 1) ? wt[g << 1] : 0u;
    partials[g * SB + li] = woff + inc - v;
  }
  // part 2: all 1024 threads scan counts2 (4 cells/thread) -> cur2 (starts)
  const int base = tid * 4;
  const unsigned c0 = counts2[base], c1 = counts2[base + 1],
                 c2 = counts2[base + 2], c3 = counts2[base + 3];
  const unsigned run = c0 + c1 + c2 + c3;
  unsigned inc2 = run;
  for (int o = 1; o < 64; o <<= 1) {
    const unsigned t = __shfl_up(inc2, o, 64);
    if ((tid & 63) >= o) inc2 += t;
  }
  if ((tid & 63) == 63) wt2[tid >> 6] = inc2;
  __syncthreads();
  if (tid < 16) {
    unsigned w = wt2[tid];
    for (int o = 1; o < 16; o <<= 1) {
      const unsigned t = __shfl_up(w, o, 16);
      if (tid >= o) w += t;
    }
    wt2[tid] = w;
  }
  __syncthreads();
  const unsigned woff2 = (tid >> 6) ? wt2[(tid >> 6) - 1] : 0u;
  unsigned r = woff2 + inc2 - run;
  cur2[base] = r; cur2[base + 1] = r + c0;
  cur2[base + 2] = r + c0 + c1; cur2[base + 3] = r + c0 + c1 + c2;
}

// Phase C: block-level exclusive scan + block offset -> cur (CSR starts).
__global__ __launch_bounds__(1024) void scan_final_kernel(
    const unsigned* __restrict__ counts0, unsigned* __restrict__ cur0,
    const unsigned* __restrict__ counts1, unsigned* __restrict__ cur1,
    const unsigned* __restrict__ partials) {
  const unsigned* counts = blockIdx.y ? counts0 : counts1;
  unsigned* cur          = blockIdx.y ? cur0    : cur1;
  const int tid = threadIdx.x;
  const int base = blockIdx.x * CHUNK + tid * 2;
  const unsigned a = counts[base], b = counts[base + 1];
  const unsigned tsum = a + b;
  unsigned inc = tsum;
  for (int o = 1; o < 64; o <<= 1) {
    const unsigned t = __shfl_up(inc, o, 64);
    if ((tid & 63) >= o) inc += t;
  }
  __shared__ unsigned wt[16];
  if ((tid & 63) == 63) wt[tid >> 6] = inc;
  __syncthreads();
  if (tid < 16) {
    unsigned w = wt[tid];
    for (int o = 1; o < 16; o <<= 1) {
      const unsigned t = __shfl_up(w, o, 16);
      if (tid >= o) w += t;
    }
    wt[tid] = w;
  }
  __syncthreads();
  const unsigned woff = (tid >> 6) ? wt[(tid >> 6) - 1] : 0u;
  const unsigned off =
      partials[blockIdx.y * SB + blockIdx.x] + woff + inc - tsum;
  cur[base] = off;
  cur[base + 1] = off + a;
}

// After scatter, cur[c] / cur2[c] = CSR inclusive end (start = cur[c-1]).
__global__ __launch_bounds__(BLOCK) void scatter_kernel(
    const float* __restrict__ pc0, const float* __restrict__ pc1,
    unsigned* __restrict__ cur0, unsigned* __restrict__ cur1,
    unsigned* __restrict__ cur2,
    float4* __restrict__ q, float4* __restrict__ s, float4* __restrict__ s2) {
  const int gid = blockIdx.x * BLOCK + threadIdx.x;
  if (gid < NPTS) {   // pc1 -> s (fine order) and s2 (coarse order)
    const float x = pc1[3 * gid], y = pc1[3 * gid + 1], z = pc1[3 * gid + 2];
    const float4 pt = make_float4(x, y, z, 0.f);
    const int cid  = (cellOf(z) * G + cellOf(y)) * G + cellOf(x);
    const int cid2 = (cellOf2(z) * G2 + cellOf2(y)) * G2 + cellOf2(x);
    s[atomicAdd(&cur1[cid], 1u)] = pt;
    s2[atomicAdd(&cur2[cid2], 1u)] = pt;
  } else {            // pc0 -> q (fine order)
    const int i = gid - NPTS;
    const float x = pc0[3 * i], y = pc0[3 * i + 1], z = pc0[3 * i + 2];
    const int cid = (cellOf(z) * G + cellOf(y)) * G + cellOf(x);
    q[atomicAdd(&cur0[cid], 1u)] = make_float4(x, y, z, 0.f);
  }
}

// Phase 1: rings 0..1 per thread on the fine grid; push unfinished to worklist.
__global__ __launch_bounds__(BLOCK) void query_kernel(
    const float4* __restrict__ q, const unsigned* __restrict__ ends,
    const float4* __restrict__ s,
    unsigned* __restrict__ wl, float* __restrict__ wlBest,
    unsigned* __restrict__ pendCnt, float* __restrict__ bkt) {
  const int i = blockIdx.x * BLOCK + threadIdx.x;
  const float4 p = q[i];
  const int cx = cellOf(p.x), cy = cellOf(p.y), cz = cellOf(p.z);
  const int x0 = max(cx - 1, 0), x1 = min(cx + 1, G - 1);

  unsigned rs[9], re[9];
#pragma unroll
  for (int rr = 0; rr < 9; ++rr) {
    const int zz = cz + rr / 3 - 1, yy = cy + rr % 3 - 1;
    const bool ok = (zz >= 0) && (zz < G) && (yy >= 0) && (yy < G);
    const int rb = ok ? (zz * G + yy) * G : 0;
    rs[rr] = ok ? ((rb + x0) ? ends[rb + x0 - 1] : 0u) : 0u;
    re[rr] = ok ? ends[rb + x1] : 0u;
  }
  float best = 3.4e38f;
#pragma unroll
  for (int rr = 0; rr < 9; ++rr) {
#pragma unroll 4
    for (unsigned j = rs[rr]; j < re[rr]; ++j) {
      const float4 c = s[j];
      const float dx = p.x - c.x, dy = p.y - c.y, dz = p.z - c.z;
      best = fminf(best, fmaf(dx, dx, fmaf(dy, dy, dz * dz)));
    }
  }

  float v = 0.f, c = 0.f;
  if (best > H * H) {            // not provably exact -> phase 2
    const unsigned k = atomicAdd(pendCnt, 1u);
    wl[k] = (unsigned)i; wlBest[k] = best;
  } else if (best <= 2.0f) { v = best; c = 1.0f; }

  for (int o = 32; o; o >>= 1) {
    v += __shfl_down(v, o, 64);
    c += __shfl_down(c, o, 64);
  }
  __shared__ float wsum[BLOCK / 64], wcnt[BLOCK / 64];
  const int wid = threadIdx.x >> 6;
  if ((threadIdx.x & 63) == 0) { wsum[wid] = v; wcnt[wid] = c; }
  __syncthreads();
  if (threadIdx.x == 0) {
    float bv = 0.f, bc = 0.f;
    for (int w = 0; w < BLOCK / 64; ++w) { bv += wsum[w]; bc += wcnt[w]; }
    if (bc != 0.f) {
      atomicAdd(&bkt[2 * (blockIdx.x & 63) + 0], bv);
      atomicAdd(&bkt[2 * (blockIdx.x & 63) + 1], bc);
    }
  }
}

// Phase 2: one wave per pending query, COARSE grid; lanes split ring segments.
// Ring 1 = full 3x3x3 (9 rows); rings 2..3 shells. r=4 head always terminates.
__global__ __launch_bounds__(BLOCK) void pending_kernel(
    const float4* __restrict__ q,
    const unsigned* __restrict__ ends2, const float4* __restrict__ s2,
    const unsigned* __restrict__ wl, const float* __restrict__ wlBest,
    unsigned* __restrict__ pendCnt, float* __restrict__ bkt,
    unsigned* __restrict__ done, float* __restrict__ out) {
  __shared__ int snP;
  __shared__ float wsum[BLOCK / 64], wcnt[BLOCK / 64];
  __shared__ int isLast;
  __shared__ float fs[BLOCK / 64], fc[BLOCK / 64];
  if (threadIdx.x == 0) snP = (int)atomicAdd(pendCnt, 0u);
  __syncthreads();
  const int lane = threadIdx.x & 63, wid = threadIdx.x >> 6;
  const int gw = blockIdx.x * (BLOCK / 64) + wid;
  const int nW = PBLOCKS * (BLOCK / 64);
  float v = 0.f, c = 0.f;

  for (int it = gw; it < snP; it += nW) {
    const unsigned qi = wl[it];
    const float4 p = q[qi];
    const int cx = cellOf2(p.x), cy = cellOf2(p.y), cz = cellOf2(p.z);
    float best = wlBest[it];   // wave-uniform (same address)

    for (int r = 1; r <= 4; ++r) {
      const float cov = H2 * (float)(r - 1);    // unscanned dist lower bound
      if (best <= cov * cov) break;             // exact
      if (best > 2.0f && cov * cov >= 2.0f) break;  // masked out either way
      const int S = (r == 1) ? 9 : 8 * r + 2 * (2 * r - 1) * (2 * r - 1);
      float b = best;
      for (int sI = lane; sI < S; sI += 64) {
        int dz, dy, xa, xb;
        if (r == 1) {                           // full 3x3x3: 9 x-rows
          dz = sI / 3 - 1; dy = sI % 3 - 1; xa = cx - 1; xb = cx + 1;
        } else if (sI < 8 * r) {                // z/y shell faces: full x rows
          if (sI < 2 * r + 1)      { dz = -r; dy = sI - r; }
          else if (sI < 4 * r + 2) { dz =  r; dy = sI - (2 * r + 1) - r; }
          else { const int t2 = sI - (4 * r + 2); dz = (t2 >> 1) - (r - 1);
                 dy = (t2 & 1) ? r : -r; }
          xa = cx - r; xb = cx + r;
        } else {                                // interior rows: x = +/- r endpoints
          const int t2 = sI - 8 * r, ci = t2 >> 1, w1 = 2 * r - 1;
          dz = ci / w1 - (r - 1); dy = ci % w1 - (r - 1);
          xa = xb = (t2 & 1) ? cx + r : cx - r;
        }
        const int zz = cz + dz, yy = cy + dy;
        if (zz < 0 || zz >= G2 || yy < 0 || yy >= G2) continue;
        const int a = max(xa, 0), e = min(xb, G2 - 1);
        if (a > e) continue;
        const int rb = (zz * G2 + yy) * G2;
        const unsigned js = (rb + a) ? ends2[rb + a - 1] : 0u;
        const unsigned je = ends2[rb + e];
        for (unsigned j = js; j < je; ++j) {
          const float4 cd = s2[j];
          const float dx = p.x - cd.x, dyv = p.y - cd.y, dzv = p.z - cd.z;
          b = fminf(b, fmaf(dx, dx, fmaf(dyv, dyv, dzv * dzv)));
        }
      }
      for (int o = 32; o; o >>= 1) b = fminf(b, __shfl_xor(b, o, 64));
      best = b;                                 // wave-uniform again
    }
    if (lane == 0 && best <= 2.0f) { v += best; c += 1.0f; }
  }

  if (lane == 0) { wsum[wid] = v; wcnt[wid] = c; }
  __syncthreads();
  if (threadIdx.x == 0) {
    float bv = 0.f, bc = 0.f;
    for (int w = 0; w < BLOCK / 64; ++w) { bv += wsum[w]; bc += wcnt[w]; }
    if (bc != 0.f) {
      atomicAdd(&bkt[2 * (blockIdx.x & 63) + 0], bv);
      atomicAdd(&bkt[2 * (blockIdx.x & 63) + 1], bc);
    }
    __threadfence();
    isLast = (atomicAdd(done, 1u) == (unsigned)(PBLOCKS - 1));
  }
  __syncthreads();
  if (isLast) {   // parallel coherent read of the 128 bucket slots + reduce
    const float val = (threadIdx.x < 128) ? atomicAdd(&bkt[threadIdx.x], 0.0f) : 0.0f;
    float sv = (threadIdx.x & 1) ? 0.f : val;
    float cv = (threadIdx.x & 1) ? val : 0.f;
    for (int o = 32; o; o >>= 1) {
      sv += __shfl_down(sv, o, 64);
      cv += __shfl_down(cv, o, 64);
    }
    if (lane == 0) { fs[wid] = sv; fc[wid] = cv; }
    __syncthreads();
    if (threadIdx.x == 0) {
      float S = 0.f, C = 0.f;
      for (int w = 0; w < BLOCK / 64; ++w) { S += fs[w]; C += fc[w]; }
      out[0] = S / C;
    }
  }
}

extern "C" void kernel_launch(void* const* d_in, const int* in_sizes, int n_in,
                              void* d_out, int out_size, void* d_ws, size_t ws_size,
                              hipStream_t stream) {
  const float* pc0 = (const float*)d_in[0];
  const float* pc1 = (const float*)d_in[1];
  float* out = (float*)d_out;

  // slab carve-up; counts1|counts0|counts2|misc contiguous -> single memset
  char* w = (char*)d_ws;
  auto nxt = [&](size_t bytes) {
    char* p = w; w += (bytes + 255) & ~(size_t)255; return p;
  };
  unsigned* counts1  = (unsigned*)nxt((size_t)NC * 4);           // 1 MB
  unsigned* counts0  = (unsigned*)nxt((size_t)NC * 4);           // 1 MB
  unsigned* counts2  = (unsigned*)nxt((size_t)NC2 * 4);          // 16 KB
  char*     misc     = nxt(1024);   // bkt[128] | done | pendCnt
  float*    bkt      = (float*)misc;
  unsigned* done     = (unsigned*)(misc + 512);
  unsigned* pendCnt  = (unsigned*)(misc + 516);
  unsigned* partials = (unsigned*)nxt((size_t)2 * SB * 4);       // 1 KB
  unsigned* cur1     = (unsigned*)nxt((size_t)NC * 4);           // 1 MB
  unsigned* cur0     = (unsigned*)nxt((size_t)NC * 4);           // 1 MB
  unsigned* cur2     = (unsigned*)nxt((size_t)NC2 * 4);          // 16 KB
  float4*   s        = (float4*)nxt((size_t)NPTS * 16);          // 1 MB
  float4*   s2       = (float4*)nxt((size_t)NPTS * 16);          // 1 MB
  float4*   q        = (float4*)nxt((size_t)NPTS * 16);          // 1 MB
  unsigned* wl       = (unsigned*)nxt((size_t)NPTS * 4);         // 256 KB
  float*    wlBest   = (float*)nxt((size_t)NPTS * 4);            // 256 KB

  hipMemsetAsync(counts1, 0, (size_t)2 * NC * 4 + (size_t)NC2 * 4 + 1024, stream);

  count_kernel<<<2 * NPTS / BLOCK, BLOCK, 0, stream>>>(pc0, pc1,
                                                       counts0, counts1, counts2);
  scan_partial_kernel<<<dim3(SB, 2), 1024, 0, stream>>>(counts0, counts1, partials);
  scan_mid_kernel<<<1, 1024, 0, stream>>>(partials, counts2, cur2);
  scan_final_kernel<<<dim3(SB, 2), 1024, 0, stream>>>(counts0, cur0,
                                                      counts1, cur1, partials);
  scatter_kernel<<<2 * NPTS / BLOCK, BLOCK, 0, stream>>>(
      pc0, pc1, cur0, cur1, cur2, q, s, s2);
  query_kernel<<<NPTS / BLOCK, BLOCK, 0, stream>>>(q, cur1, s, wl, wlBest,
                                                   pendCnt, bkt);
  pending_kernel<<<PBLOCKS, BLOCK, 0, stream>>>(q, cur2, s2, wl, wlBest,
                                                pendCnt, bkt, done, out);
}

// Round 16
// 154.171 us; speedup vs baseline: 2.0181x; 2.0181x over previous
//
#include <hip/hip_runtime.h>

// Chamfer forward: dist0[i] = min_j ||pc0[i]-pc1[j]||^2 ; out = mean(dist0[dist0<=2])
// N = M = 65536 i.i.d. N(0,1)^3 points, fp32.
// Fine grid G=64 (h=0.125) phase 1 + MEDIUM grid G3=32 (h3=0.25) phase 2.
// ROUND 16: R15's coarse (h2=0.5) phase 2 regressed (ring-1 candidate volume 3.4
// unit^3 -> thousands of pts); R14's fine phase 2 had ~170 serial segment batches.
// Medium h3=0.25 balances both: r_max=7, worst ~16 serial batches, ring-1 volume
// 0.42 unit^3. Build fused: count bumps 32^3 histogram; multi-block scan grows a
// third y-slice (16 blocks); scan_mid scans its 16 partials; scatter writes s3.

constexpr int   NPTS  = 65536;
constexpr int   G     = 64;
constexpr int   NC    = G * G * G;    // 262144 fine cells
constexpr float H     = 0.125f;
constexpr float ORG   = -4.0f;
constexpr float INVH  = 8.0f;
constexpr int   G3    = 32;           // medium grid (phase 2)
constexpr int   NC3   = G3 * G3 * G3; // 32768 cells
constexpr float H3    = 0.25f;
constexpr float INVH3 = 4.0f;
constexpr int   BLOCK = 256;
constexpr int   PBLOCKS = 256;        // pending kernel grid (done-counter)
constexpr int   SB    = 128;          // scan blocks for fine arrays
constexpr int   SB3   = 16;           // scan blocks for medium array
constexpr int   CHUNK = NC / SB;      // 2048 counts per scan block (2/thread)

__device__ __forceinline__ int cellOf(float x) {
  int c = (int)floorf((x - ORG) * INVH);
  return min(max(c, 0), G - 1);
}
__device__ __forceinline__ int cellOf3(float x) {
  int c = (int)floorf((x - ORG) * INVH3);
  return min(max(c, 0), G3 - 1);
}

__global__ __launch_bounds__(BLOCK) void count_kernel(
    const float* __restrict__ pc0, const float* __restrict__ pc1,
    unsigned* __restrict__ counts0, unsigned* __restrict__ counts1,
    unsigned* __restrict__ counts3) {
  const int gid = blockIdx.x * BLOCK + threadIdx.x;
  if (gid < NPTS) {   // pc1: fine + medium histograms
    const float x = pc1[3 * gid], y = pc1[3 * gid + 1], z = pc1[3 * gid + 2];
    atomicAdd(&counts1[(cellOf(z) * G + cellOf(y)) * G + cellOf(x)], 1u);
    atomicAdd(&counts3[(cellOf3(z) * G3 + cellOf3(y)) * G3 + cellOf3(x)], 1u);
  } else {            // pc0: fine only
    const int i = gid - NPTS;
    const float x = pc0[3 * i], y = pc0[3 * i + 1], z = pc0[3 * i + 2];
    atomicAdd(&counts0[(cellOf(z) * G + cellOf(y)) * G + cellOf(x)], 1u);
  }
}

// Phase A: per-block partial sums. grid=(SB,3); y=0->counts1, y=1->counts0,
// y=2->counts3 (only SB3 blocks active). partials: [0..127|128..255|256..271].
__global__ __launch_bounds__(1024) void scan_partial_kernel(
    const unsigned* __restrict__ counts0, const unsigned* __restrict__ counts1,
    const unsigned* __restrict__ counts3, unsigned* __restrict__ partials) {
  if (blockIdx.y == 2 && blockIdx.x >= SB3) return;
  const unsigned* counts = (blockIdx.y == 0) ? counts1
                         : (blockIdx.y == 1) ? counts0 : counts3;
  const int base = blockIdx.x * CHUNK + threadIdx.x * 2;
  unsigned sum = counts[base] + counts[base + 1];
  for (int o = 32; o; o >>= 1) sum += __shfl_down(sum, o, 64);
  __shared__ unsigned ws[16];
  if ((threadIdx.x & 63) == 0) ws[threadIdx.x >> 6] = sum;
  __syncthreads();
  if (threadIdx.x == 0) {
    unsigned t = 0;
    for (int w = 0; w < 16; ++w) t += ws[w];
    partials[blockIdx.y * SB + blockIdx.x] = t;   // y=2 -> 256+x, x<16
  }
}

// Phase B (1 block): exclusive-scan the 2x128 fine partials + 16 medium partials.
__global__ __launch_bounds__(1024) void scan_mid_kernel(
    unsigned* __restrict__ partials) {
  __shared__ unsigned wt[4];
  const int tid = threadIdx.x;
  unsigned v = 0, inc = 0; int g = 0, li = 0;
  if (tid < 256) {                 // two 128-entry arrays (waves 0-3)
    g = tid >> 7; li = tid & 127;
    v = partials[g * SB + li];
    inc = v;
    for (int o = 1; o < 64; o <<= 1) {
      const unsigned t = __shfl_up(inc, o, 64);
      if ((tid & 63) >= o) inc += t;
    }
    if ((tid & 63) == 63) wt[tid >> 6] = inc;
  } else if (tid < 256 + SB3) {    // 16-entry medium array (wave 4, lanes 0-15)
    v = partials[256 + (tid - 256)];
    inc = v;
    for (int o = 1; o < 16; o <<= 1) {
      const unsigned t = __shfl_up(inc, o, 64);
      if ((tid & 63) >= o) inc += t;
    }
  }
  __syncthreads();
  if (tid < 256) {
    const unsigned woff = ((tid >> 6) & 1) ? wt[g << 1] : 0u;
    partials[g * SB + li] = woff + inc - v;
  } else if (tid < 256 + SB3) {
    partials[256 + (tid - 256)] = inc - v;
  }
}

// Phase C: block scan + offset -> cur (CSR starts). grid=(SB,3) as in phase A.
__global__ __launch_bounds__(1024) void scan_final_kernel(
    const unsigned* __restrict__ counts0, unsigned* __restrict__ cur0,
    const unsigned* __restrict__ counts1, unsigned* __restrict__ cur1,
    const unsigned* __restrict__ counts3, unsigned* __restrict__ cur3,
    const unsigned* __restrict__ partials) {
  if (blockIdx.y == 2 && blockIdx.x >= SB3) return;
  const unsigned* counts = (blockIdx.y == 0) ? counts1
                         : (blockIdx.y == 1) ? counts0 : counts3;
  unsigned* cur          = (blockIdx.y == 0) ? cur1
                         : (blockIdx.y == 1) ? cur0 : cur3;
  const int tid = threadIdx.x;
  const int base = blockIdx.x * CHUNK + tid * 2;
  const unsigned a = counts[base], b = counts[base + 1];
  const unsigned tsum = a + b;
  unsigned inc = tsum;
  for (int o = 1; o < 64; o <<= 1) {
    const unsigned t = __shfl_up(inc, o, 64);
    if ((tid & 63) >= o) inc += t;
  }
  __shared__ unsigned wt[16];
  if ((tid & 63) == 63) wt[tid >> 6] = inc;
  __syncthreads();
  if (tid < 16) {
    unsigned w = wt[tid];
    for (int o = 1; o < 16; o <<= 1) {
      const unsigned t = __shfl_up(w, o, 16);
      if (tid >= o) w += t;
    }
    wt[tid] = w;
  }
  __syncthreads();
  const unsigned woff = (tid >> 6) ? wt[(tid >> 6) - 1] : 0u;
  const unsigned off =
      partials[blockIdx.y * SB + blockIdx.x] + woff + inc - tsum;
  cur[base] = off;
  cur[base + 1] = off + a;
}

// After scatter, cur[c]/cur3[c] = CSR inclusive end (start = cur[c-1]).
__global__ __launch_bounds__(BLOCK) void scatter_kernel(
    const float* __restrict__ pc0, const float* __restrict__ pc1,
    unsigned* __restrict__ cur0, unsigned* __restrict__ cur1,
    unsigned* __restrict__ cur3,
    float4* __restrict__ q, float4* __restrict__ s, float4* __restrict__ s3) {
  const int gid = blockIdx.x * BLOCK + threadIdx.x;
  if (gid < NPTS) {   // pc1 -> s (fine order) and s3 (medium order)
    const float x = pc1[3 * gid], y = pc1[3 * gid + 1], z = pc1[3 * gid + 2];
    const float4 pt = make_float4(x, y, z, 0.f);
    const int cid  = (cellOf(z) * G + cellOf(y)) * G + cellOf(x);
    const int cid3 = (cellOf3(z) * G3 + cellOf3(y)) * G3 + cellOf3(x);
    s[atomicAdd(&cur1[cid], 1u)] = pt;
    s3[atomicAdd(&cur3[cid3], 1u)] = pt;
  } else {            // pc0 -> q (fine order)
    const int i = gid - NPTS;
    const float x = pc0[3 * i], y = pc0[3 * i + 1], z = pc0[3 * i + 2];
    const int cid = (cellOf(z) * G + cellOf(y)) * G + cellOf(x);
    q[atomicAdd(&cur0[cid], 1u)] = make_float4(x, y, z, 0.f);
  }
}

// Phase 1: fine rings 0..1 per thread; push unfinished to worklist.
__global__ __launch_bounds__(BLOCK) void query_kernel(
    const float4* __restrict__ q, const unsigned* __restrict__ ends,
    const float4* __restrict__ s,
    unsigned* __restrict__ wl, float* __restrict__ wlBest,
    unsigned* __restrict__ pendCnt, float* __restrict__ bkt) {
  const int i = blockIdx.x * BLOCK + threadIdx.x;
  const float4 p = q[i];
  const int cx = cellOf(p.x), cy = cellOf(p.y), cz = cellOf(p.z);
  const int x0 = max(cx - 1, 0), x1 = min(cx + 1, G - 1);

  unsigned rs[9], re[9];
#pragma unroll
  for (int rr = 0; rr < 9; ++rr) {
    const int zz = cz + rr / 3 - 1, yy = cy + rr % 3 - 1;
    const bool ok = (zz >= 0) && (zz < G) && (yy >= 0) && (yy < G);
    const int rb = ok ? (zz * G + yy) * G : 0;
    rs[rr] = ok ? ((rb + x0) ? ends[rb + x0 - 1] : 0u) : 0u;
    re[rr] = ok ? ends[rb + x1] : 0u;
  }
  float best = 3.4e38f;
#pragma unroll
  for (int rr = 0; rr < 9; ++rr) {
#pragma unroll 4
    for (unsigned j = rs[rr]; j < re[rr]; ++j) {
      const float4 c = s[j];
      const float dx = p.x - c.x, dy = p.y - c.y, dz = p.z - c.z;
      best = fminf(best, fmaf(dx, dx, fmaf(dy, dy, dz * dz)));
    }
  }

  float v = 0.f, c = 0.f;
  if (best > H * H) {            // not provably exact -> phase 2
    const unsigned k = atomicAdd(pendCnt, 1u);
    wl[k] = (unsigned)i; wlBest[k] = best;
  } else if (best <= 2.0f) { v = best; c = 1.0f; }

  for (int o = 32; o; o >>= 1) {
    v += __shfl_down(v, o, 64);
    c += __shfl_down(c, o, 64);
  }
  __shared__ float wsum[BLOCK / 64], wcnt[BLOCK / 64];
  const int wid = threadIdx.x >> 6;
  if ((threadIdx.x & 63) == 0) { wsum[wid] = v; wcnt[wid] = c; }
  __syncthreads();
  if (threadIdx.x == 0) {
    float bv = 0.f, bc = 0.f;
    for (int w = 0; w < BLOCK / 64; ++w) { bv += wsum[w]; bc += wcnt[w]; }
    if (bc != 0.f) {
      atomicAdd(&bkt[2 * (blockIdx.x & 63) + 0], bv);
      atomicAdd(&bkt[2 * (blockIdx.x & 63) + 1], bc);
    }
  }
}

// Phase 2: one wave per pending query on the MEDIUM grid; lanes split segments.
// Ring 1 = full 3x3x3 (9 rows); rings 2.. shells; r=7 head always terminates
// (cov^2 = (6*0.25)^2 = 2.25 > 2 -> exact-break or masked-break).
__global__ __launch_bounds__(BLOCK) void pending_kernel(
    const float4* __restrict__ q,
    const unsigned* __restrict__ ends3, const float4* __restrict__ s3,
    const unsigned* __restrict__ wl, const float* __restrict__ wlBest,
    unsigned* __restrict__ pendCnt, float* __restrict__ bkt,
    unsigned* __restrict__ done, float* __restrict__ out) {
  __shared__ int snP;
  __shared__ float wsum[BLOCK / 64], wcnt[BLOCK / 64];
  __shared__ int isLast;
  __shared__ float fs[BLOCK / 64], fc[BLOCK / 64];
  if (threadIdx.x == 0) snP = (int)atomicAdd(pendCnt, 0u);
  __syncthreads();
  const int lane = threadIdx.x & 63, wid = threadIdx.x >> 6;
  const int gw = blockIdx.x * (BLOCK / 64) + wid;
  const int nW = PBLOCKS * (BLOCK / 64);
  float v = 0.f, c = 0.f;

  for (int it = gw; it < snP; it += nW) {
    const unsigned qi = wl[it];
    const float4 p = q[qi];
    const int cx = cellOf3(p.x), cy = cellOf3(p.y), cz = cellOf3(p.z);
    float best = wlBest[it];   // wave-uniform (same address)

    for (int r = 1; r <= 8; ++r) {
      const float cov = H3 * (float)(r - 1);    // unscanned dist lower bound
      if (best <= cov * cov) break;             // exact
      if (best > 2.0f && cov * cov >= 2.0f) break;  // masked out either way
      const int S = (r == 1) ? 9 : 8 * r + 2 * (2 * r - 1) * (2 * r - 1);
      float b = best;
      for (int sI = lane; sI < S; sI += 64) {
        int dz, dy, xa, xb;
        if (r == 1) {                           // full 3x3x3: 9 x-rows
          dz = sI / 3 - 1; dy = sI % 3 - 1; xa = cx - 1; xb = cx + 1;
        } else if (sI < 8 * r) {                // z/y shell faces: full x rows
          if (sI < 2 * r + 1)      { dz = -r; dy = sI - r; }
          else if (sI < 4 * r + 2) { dz =  r; dy = sI - (2 * r + 1) - r; }
          else { const int t2 = sI - (4 * r + 2); dz = (t2 >> 1) - (r - 1);
                 dy = (t2 & 1) ? r : -r; }
          xa = cx - r; xb = cx + r;
        } else {                                // interior rows: x = +/- r endpoints
          const int t2 = sI - 8 * r, ci = t2 >> 1, w1 = 2 * r - 1;
          dz = ci / w1 - (r - 1); dy = ci % w1 - (r - 1);
          xa = xb = (t2 & 1) ? cx + r : cx - r;
        }
        const int zz = cz + dz, yy = cy + dy;
        if (zz < 0 || zz >= G3 || yy < 0 || yy >= G3) continue;
        const int a = max(xa, 0), e = min(xb, G3 - 1);
        if (a > e) continue;
        const int rb = (zz * G3 + yy) * G3;
        const unsigned js = (rb + a) ? ends3[rb + a - 1] : 0u;
        const unsigned je = ends3[rb + e];
        for (unsigned j = js; j < je; ++j) {
          const float4 cd = s3[j];
          const float dx = p.x - cd.x, dyv = p.y - cd.y, dzv = p.z - cd.z;
          b = fminf(b, fmaf(dx, dx, fmaf(dyv, dyv, dzv * dzv)));
        }
      }
      for (int o = 32; o; o >>= 1) b = fminf(b, __shfl_xor(b, o, 64));
      best = b;                                 // wave-uniform again
    }
    if (lane == 0 && best <= 2.0f) { v += best; c += 1.0f; }
  }

  if (lane == 0) { wsum[wid] = v; wcnt[wid] = c; }
  __syncthreads();
  if (threadIdx.x == 0) {
    float bv = 0.f, bc = 0.f;
    for (int w = 0; w < BLOCK / 64; ++w) { bv += wsum[w]; bc += wcnt[w]; }
    if (bc != 0.f) {
      atomicAdd(&bkt[2 * (blockIdx.x & 63) + 0], bv);
      atomicAdd(&bkt[2 * (blockIdx.x & 63) + 1], bc);
    }
    __threadfence();
    isLast = (atomicAdd(done, 1u) == (unsigned)(PBLOCKS - 1));
  }
  __syncthreads();
  if (isLast) {   // parallel coherent read of the 128 bucket slots + reduce
    const float val = (threadIdx.x < 128) ? atomicAdd(&bkt[threadIdx.x], 0.0f) : 0.0f;
    float sv = (threadIdx.x & 1) ? 0.f : val;
    float cv = (threadIdx.x & 1) ? val : 0.f;
    for (int o = 32; o; o >>= 1) {
      sv += __shfl_down(sv, o, 64);
      cv += __shfl_down(cv, o, 64);
    }
    if (lane == 0) { fs[wid] = sv; fc[wid] = cv; }
    __syncthreads();
    if (threadIdx.x == 0) {
      float S = 0.f, C = 0.f;
      for (int w = 0; w < BLOCK / 64; ++w) { S += fs[w]; C += fc[w]; }
      out[0] = S / C;
    }
  }
}

extern "C" void kernel_launch(void* const* d_in, const int* in_sizes, int n_in,
                              void* d_out, int out_size, void* d_ws, size_t ws_size,
                              hipStream_t stream) {
  const float* pc0 = (const float*)d_in[0];
  const float* pc1 = (const float*)d_in[1];
  float* out = (float*)d_out;

  // slab carve-up; counts1|counts0|counts3|misc contiguous -> single memset
  char* w = (char*)d_ws;
  auto nxt = [&](size_t bytes) {
    char* p = w; w += (bytes + 255) & ~(size_t)255; return p;
  };
  unsigned* counts1  = (unsigned*)nxt((size_t)NC * 4);           // 1 MB
  unsigned* counts0  = (unsigned*)nxt((size_t)NC * 4);           // 1 MB
  unsigned* counts3  = (unsigned*)nxt((size_t)NC3 * 4);          // 128 KB
  char*     misc     = nxt(1024);   // bkt[128] | done | pendCnt
  float*    bkt      = (float*)misc;
  unsigned* done     = (unsigned*)(misc + 512);
  unsigned* pendCnt  = (unsigned*)(misc + 516);
  unsigned* partials = (unsigned*)nxt((size_t)(2 * SB + SB3) * 4);
  unsigned* cur1     = (unsigned*)nxt((size_t)NC * 4);           // 1 MB
  unsigned* cur0     = (unsigned*)nxt((size_t)NC * 4);           // 1 MB
  unsigned* cur3     = (unsigned*)nxt((size_t)NC3 * 4);          // 128 KB
  float4*   s        = (float4*)nxt((size_t)NPTS * 16);          // 1 MB
  float4*   s3       = (float4*)nxt((size_t)NPTS * 16);          // 1 MB
  float4*   q        = (float4*)nxt((size_t)NPTS * 16);          // 1 MB
  unsigned* wl       = (unsigned*)nxt((size_t)NPTS * 4);         // 256 KB
  float*    wlBest   = (float*)nxt((size_t)NPTS * 4);            // 256 KB

  hipMemsetAsync(counts1, 0, (size_t)2 * NC * 4 + (size_t)NC3 * 4 + 1024, stream);

  count_kernel<<<2 * NPTS / BLOCK, BLOCK, 0, stream>>>(pc0, pc1,
                                                       counts0, counts1, counts3);
  scan_partial_kernel<<<dim3(SB, 3), 1024, 0, stream>>>(counts0, counts1,
                                                        counts3, partials);
  scan_mid_kernel<<<1, 1024, 0, stream>>>(partials);
  scan_final_kernel<<<dim3(SB, 3), 1024, 0, stream>>>(counts0, cur0,
                                                      counts1, cur1,
                                                      counts3, cur3, partials);
  scatter_kernel<<<2 * NPTS / BLOCK, BLOCK, 0, stream>>>(
      pc0, pc1, cur0, cur1, cur3, q, s, s3);
  query_kernel<<<NPTS / BLOCK, BLOCK, 0, stream>>>(q, cur1, s, wl, wlBest,
                                                   pendCnt, bkt);
  pending_kernel<<<PBLOCKS, BLOCK, 0, stream>>>(q, cur3, s3, wl, wlBest,
                                                pendCnt, bkt, done, out);
}

// Round 17
// 152.728 us; speedup vs baseline: 2.0371x; 1.0095x over previous
//
#include <hip/hip_runtime.h>

// Chamfer forward: dist0[i] = min_j ||pc0[i]-pc1[j]||^2 ; out = mean(dist0[dist0<=2])
// N = M = 65536 i.i.d. N(0,1)^3 points, fp32.
// Fine grid G=64 (h=0.125), counting sort, two-phase query (R16: 154us).
// ROUND 17: (1) dropped the separate medium-grid build: a medium cell (h3=0.25)
// is a 2x2x2 block of fine cells, so pending keeps medium ring GEOMETRY but reads
// 4 fine CSR rows per medium row -> deletes counts3/cur3/s3 (one atomic per pc1
// point in count, a scan slice, one atomic+write in scatter, 128KB memset).
// (2) query: 2 lanes per query (512 blocks = 8 waves/SIMD) halves the per-lane
// serial candidate chain (~39 -> ~20 dependent L2 loads).
// Top remaining dispatch is the harness's 268MB ws poison (~40us) - not ours.

constexpr int   NPTS  = 65536;
constexpr int   G     = 64;
constexpr int   NC    = G * G * G;    // 262144 fine cells
constexpr float H     = 0.125f;
constexpr float ORG   = -4.0f;
constexpr float INVH  = 8.0f;
constexpr int   G3    = 32;           // medium geometry (phase 2 rings)
constexpr float H3    = 0.25f;
constexpr float INVH3 = 4.0f;
constexpr int   BLOCK = 256;
constexpr int   PBLOCKS = 256;        // pending kernel grid (done-counter)
constexpr int   SB    = 128;          // scan blocks per fine array
constexpr int   CHUNK = NC / SB;      // 2048 counts per scan block (2/thread)

__device__ __forceinline__ int cellOf(float x) {
  int c = (int)floorf((x - ORG) * INVH);
  return min(max(c, 0), G - 1);
}
__device__ __forceinline__ int cellOf3(float x) {
  int c = (int)floorf((x - ORG) * INVH3);
  return min(max(c, 0), G3 - 1);
}

__global__ __launch_bounds__(BLOCK) void count_kernel(
    const float* __restrict__ pc0, const float* __restrict__ pc1,
    unsigned* __restrict__ counts0, unsigned* __restrict__ counts1) {
  const int gid = blockIdx.x * BLOCK + threadIdx.x;
  const float* p; unsigned* cnt; int i;
  if (gid < NPTS) { p = pc1; cnt = counts1; i = gid; }
  else            { p = pc0; cnt = counts0; i = gid - NPTS; }
  const float x = p[3 * i], y = p[3 * i + 1], z = p[3 * i + 2];
  atomicAdd(&cnt[(cellOf(z) * G + cellOf(y)) * G + cellOf(x)], 1u);
}

// Phase A: per-block partial sums. grid=(SB,2); y=0->counts1, y=1->counts0.
__global__ __launch_bounds__(1024) void scan_partial_kernel(
    const unsigned* __restrict__ counts0, const unsigned* __restrict__ counts1,
    unsigned* __restrict__ partials) {
  const unsigned* counts = blockIdx.y ? counts0 : counts1;
  const int base = blockIdx.x * CHUNK + threadIdx.x * 2;
  unsigned sum = counts[base] + counts[base + 1];
  for (int o = 32; o; o >>= 1) sum += __shfl_down(sum, o, 64);
  __shared__ unsigned ws[16];
  if ((threadIdx.x & 63) == 0) ws[threadIdx.x >> 6] = sum;
  __syncthreads();
  if (threadIdx.x == 0) {
    unsigned t = 0;
    for (int w = 0; w < 16; ++w) t += ws[w];
    partials[blockIdx.y * SB + blockIdx.x] = t;
  }
}

// Phase B: one 256-thread block exclusively scans both 128-entry partial arrays.
__global__ __launch_bounds__(256) void scan_mid_kernel(
    unsigned* __restrict__ partials) {
  const int tid = threadIdx.x;
  const int g   = tid >> 7;
  const int li  = tid & 127;
  const unsigned v = partials[g * SB + li];
  unsigned inc = v;
  for (int o = 1; o < 64; o <<= 1) {
    const unsigned t = __shfl_up(inc, o, 64);
    if ((tid & 63) >= o) inc += t;
  }
  __shared__ unsigned wt[4];
  if ((tid & 63) == 63) wt[tid >> 6] = inc;
  __syncthreads();
  const unsigned woff = ((tid >> 6) & 1) ? wt[g << 1] : 0u;
  partials[g * SB + li] = woff + inc - v;
}

// Phase C: block scan + offset -> cur (CSR starts). grid=(SB,2).
__global__ __launch_bounds__(1024) void scan_final_kernel(
    const unsigned* __restrict__ counts0, unsigned* __restrict__ cur0,
    const unsigned* __restrict__ counts1, unsigned* __restrict__ cur1,
    const unsigned* __restrict__ partials) {
  const unsigned* counts = blockIdx.y ? counts0 : counts1;
  unsigned* cur          = blockIdx.y ? cur0    : cur1;
  const int tid = threadIdx.x;
  const int base = blockIdx.x * CHUNK + tid * 2;
  const unsigned a = counts[base], b = counts[base + 1];
  const unsigned tsum = a + b;
  unsigned inc = tsum;
  for (int o = 1; o < 64; o <<= 1) {
    const unsigned t = __shfl_up(inc, o, 64);
    if ((tid & 63) >= o) inc += t;
  }
  __shared__ unsigned wt[16];
  if ((tid & 63) == 63) wt[tid >> 6] = inc;
  __syncthreads();
  if (tid < 16) {
    unsigned w = wt[tid];
    for (int o = 1; o < 16; o <<= 1) {
      const unsigned t = __shfl_up(w, o, 16);
      if (tid >= o) w += t;
    }
    wt[tid] = w;
  }
  __syncthreads();
  const unsigned woff = (tid >> 6) ? wt[(tid >> 6) - 1] : 0u;
  const unsigned off =
      partials[blockIdx.y * SB + blockIdx.x] + woff + inc - tsum;
  cur[base] = off;
  cur[base + 1] = off + a;
}

// After scatter, cur[c] = CSR inclusive end of cell c (start = cur[c-1]).
__global__ __launch_bounds__(BLOCK) void scatter_kernel(
    const float* __restrict__ pc0, const float* __restrict__ pc1,
    unsigned* __restrict__ cur0, unsigned* __restrict__ cur1,
    float4* __restrict__ q, float4* __restrict__ s) {
  const int gid = blockIdx.x * BLOCK + threadIdx.x;
  const float* p; unsigned* cur; float4* dst; int i;
  if (gid < NPTS) { p = pc1; cur = cur1; dst = s; i = gid; }
  else            { p = pc0; cur = cur0; dst = q; i = gid - NPTS; }
  const float x = p[3 * i], y = p[3 * i + 1], z = p[3 * i + 2];
  const int cid = (cellOf(z) * G + cellOf(y)) * G + cellOf(x);
  dst[atomicAdd(&cur[cid], 1u)] = make_float4(x, y, z, 0.f);
}

// Phase 1: fine rings 0..1, 2 lanes per query; push unfinished to worklist.
__global__ __launch_bounds__(BLOCK) void query_kernel(
    const float4* __restrict__ q, const unsigned* __restrict__ ends,
    const float4* __restrict__ s,
    unsigned* __restrict__ wl, float* __restrict__ wlBest,
    unsigned* __restrict__ pendCnt, float* __restrict__ bkt) {
  const int gtid = blockIdx.x * BLOCK + threadIdx.x;
  const int i   = gtid >> 1;        // query index
  const int sub = gtid & 1;         // sub-lane
  const float4 p = q[i];
  const int cx = cellOf(p.x), cy = cellOf(p.y), cz = cellOf(p.z);
  const int x0 = max(cx - 1, 0), x1 = min(cx + 1, G - 1);

  unsigned rs[9], re[9];
#pragma unroll
  for (int rr = 0; rr < 9; ++rr) {
    const int zz = cz + rr / 3 - 1, yy = cy + rr % 3 - 1;
    const bool ok = (zz >= 0) && (zz < G) && (yy >= 0) && (yy < G);
    const int rb = ok ? (zz * G + yy) * G : 0;
    rs[rr] = ok ? ((rb + x0) ? ends[rb + x0 - 1] : 0u) : 0u;
    re[rr] = ok ? ends[rb + x1] : 0u;
  }
  float best = 3.4e38f;
#pragma unroll
  for (int rr = 0; rr < 9; ++rr) {
#pragma unroll 4
    for (unsigned j = rs[rr] + sub; j < re[rr]; j += 2) {
      const float4 c = s[j];
      const float dx = p.x - c.x, dy = p.y - c.y, dz = p.z - c.z;
      best = fminf(best, fmaf(dx, dx, fmaf(dy, dy, dz * dz)));
    }
  }
  best = fminf(best, __shfl_xor(best, 1, 64));   // combine the 2 sub-lanes

  float v = 0.f, c = 0.f;
  if (sub == 0) {
    if (best > H * H) {            // not provably exact -> phase 2
      const unsigned k = atomicAdd(pendCnt, 1u);
      wl[k] = (unsigned)i; wlBest[k] = best;
    } else if (best <= 2.0f) { v = best; c = 1.0f; }
  }

  for (int o = 32; o; o >>= 1) {
    v += __shfl_down(v, o, 64);
    c += __shfl_down(c, o, 64);
  }
  __shared__ float wsum[BLOCK / 64], wcnt[BLOCK / 64];
  const int wid = threadIdx.x >> 6;
  if ((threadIdx.x & 63) == 0) { wsum[wid] = v; wcnt[wid] = c; }
  __syncthreads();
  if (threadIdx.x == 0) {
    float bv = 0.f, bc = 0.f;
    for (int w = 0; w < BLOCK / 64; ++w) { bv += wsum[w]; bc += wcnt[w]; }
    if (bc != 0.f) {
      atomicAdd(&bkt[2 * (blockIdx.x & 63) + 0], bv);
      atomicAdd(&bkt[2 * (blockIdx.x & 63) + 1], bc);
    }
  }
}

// Phase 2: one wave per pending query; MEDIUM ring geometry over the FINE CSR
// (one medium row = 4 fine rows: zz in {2Z,2Z+1}, yy in {2Y,2Y+1}, x in
// [2Xa, 2Xb+1]). Ring 1 = full 3x3x3 medium; r=8 head always terminates.
__global__ __launch_bounds__(BLOCK) void pending_kernel(
    const float4* __restrict__ q,
    const unsigned* __restrict__ ends, const float4* __restrict__ s,
    const unsigned* __restrict__ wl, const float* __restrict__ wlBest,
    unsigned* __restrict__ pendCnt, float* __restrict__ bkt,
    unsigned* __restrict__ done, float* __restrict__ out) {
  __shared__ int snP;
  __shared__ float wsum[BLOCK / 64], wcnt[BLOCK / 64];
  __shared__ int isLast;
  __shared__ float fs[BLOCK / 64], fc[BLOCK / 64];
  if (threadIdx.x == 0) snP = (int)atomicAdd(pendCnt, 0u);
  __syncthreads();
  const int lane = threadIdx.x & 63, wid = threadIdx.x >> 6;
  const int gw = blockIdx.x * (BLOCK / 64) + wid;
  const int nW = PBLOCKS * (BLOCK / 64);
  float v = 0.f, c = 0.f;

  for (int it = gw; it < snP; it += nW) {
    const unsigned qi = wl[it];
    const float4 p = q[qi];
    const int cx = cellOf3(p.x), cy = cellOf3(p.y), cz = cellOf3(p.z);
    float best = wlBest[it];   // wave-uniform (same address)

    for (int r = 1; r <= 8; ++r) {
      const float cov = H3 * (float)(r - 1);    // unscanned dist lower bound
      if (best <= cov * cov) break;             // exact
      if (best > 2.0f && cov * cov >= 2.0f) break;  // masked out either way
      const int S = (r == 1) ? 9 : 8 * r + 2 * (2 * r - 1) * (2 * r - 1);
      float b = best;
      for (int sI = lane; sI < S; sI += 64) {
        int dz, dy, xa, xb;
        if (r == 1) {                           // full 3x3x3 medium rows
          dz = sI / 3 - 1; dy = sI % 3 - 1; xa = cx - 1; xb = cx + 1;
        } else if (sI < 8 * r) {                // shell faces: full x rows
          if (sI < 2 * r + 1)      { dz = -r; dy = sI - r; }
          else if (sI < 4 * r + 2) { dz =  r; dy = sI - (2 * r + 1) - r; }
          else { const int t2 = sI - (4 * r + 2); dz = (t2 >> 1) - (r - 1);
                 dy = (t2 & 1) ? r : -r; }
          xa = cx - r; xb = cx + r;
        } else {                                // interior rows: x = +/- r ends
          const int t2 = sI - 8 * r, ci = t2 >> 1, w1 = 2 * r - 1;
          dz = ci / w1 - (r - 1); dy = ci % w1 - (r - 1);
          xa = xb = (t2 & 1) ? cx + r : cx - r;
        }
        const int Z = cz + dz, Y = cy + dy;
        if (Z < 0 || Z >= G3 || Y < 0 || Y >= G3) continue;
        const int a3 = max(xa, 0), e3 = min(xb, G3 - 1);
        if (a3 > e3) continue;
        const int xs = 2 * a3, xe = 2 * e3 + 1; // fine x-span
        // 4 fine rows per medium row; ranges preloaded (independent loads)
        unsigned js[4], je[4];
#pragma unroll
        for (int k = 0; k < 4; ++k) {
          const int zz = 2 * Z + (k >> 1), yy = 2 * Y + (k & 1);
          const int rb = (zz * G + yy) * G;
          js[k] = (rb + xs) ? ends[rb + xs - 1] : 0u;
          je[k] = ends[rb + xe];
        }
#pragma unroll
        for (int k = 0; k < 4; ++k) {
          for (unsigned j = js[k]; j < je[k]; ++j) {
            const float4 cd = s[j];
            const float dx = p.x - cd.x, dyv = p.y - cd.y, dzv = p.z - cd.z;
            b = fminf(b, fmaf(dx, dx, fmaf(dyv, dyv, dzv * dzv)));
          }
        }
      }
      for (int o = 32; o; o >>= 1) b = fminf(b, __shfl_xor(b, o, 64));
      best = b;                                 // wave-uniform again
    }
    if (lane == 0 && best <= 2.0f) { v += best; c += 1.0f; }
  }

  if (lane == 0) { wsum[wid] = v; wcnt[wid] = c; }
  __syncthreads();
  if (threadIdx.x == 0) {
    float bv = 0.f, bc = 0.f;
    for (int w = 0; w < BLOCK / 64; ++w) { bv += wsum[w]; bc += wcnt[w]; }
    if (bc != 0.f) {
      atomicAdd(&bkt[2 * (blockIdx.x & 63) + 0], bv);
      atomicAdd(&bkt[2 * (blockIdx.x & 63) + 1], bc);
    }
    __threadfence();
    isLast = (atomicAdd(done, 1u) == (unsigned)(PBLOCKS - 1));
  }
  __syncthreads();
  if (isLast) {   // parallel coherent read of the 128 bucket slots + reduce
    const float val = (threadIdx.x < 128) ? atomicAdd(&bkt[threadIdx.x], 0.0f) : 0.0f;
    float sv = (threadIdx.x & 1) ? 0.f : val;
    float cv = (threadIdx.x & 1) ? val : 0.f;
    for (int o = 32; o; o >>= 1) {
      sv += __shfl_down(sv, o, 64);
      cv += __shfl_down(cv, o, 64);
    }
    if (lane == 0) { fs[wid] = sv; fc[wid] = cv; }
    __syncthreads();
    if (threadIdx.x == 0) {
      float S = 0.f, C = 0.f;
      for (int w = 0; w < BLOCK / 64; ++w) { S += fs[w]; C += fc[w]; }
      out[0] = S / C;
    }
  }
}

extern "C" void kernel_launch(void* const* d_in, const int* in_sizes, int n_in,
                              void* d_out, int out_size, void* d_ws, size_t ws_size,
                              hipStream_t stream) {
  const float* pc0 = (const float*)d_in[0];
  const float* pc1 = (const float*)d_in[1];
  float* out = (float*)d_out;

  // slab carve-up; counts1|counts0|misc contiguous -> single memset
  char* w = (char*)d_ws;
  auto nxt = [&](size_t bytes) {
    char* p = w; w += (bytes + 255) & ~(size_t)255; return p;
  };
  unsigned* counts1  = (unsigned*)nxt((size_t)NC * 4);           // 1 MB
  unsigned* counts0  = (unsigned*)nxt((size_t)NC * 4);           // 1 MB
  char*     misc     = nxt(1024);   // bkt[128] | done | pendCnt
  float*    bkt      = (float*)misc;
  unsigned* done     = (unsigned*)(misc + 512);
  unsigned* pendCnt  = (unsigned*)(misc + 516);
  unsigned* partials = (unsigned*)nxt((size_t)2 * SB * 4);       // 1 KB
  unsigned* cur1     = (unsigned*)nxt((size_t)NC * 4);           // 1 MB
  unsigned* cur0     = (unsigned*)nxt((size_t)NC * 4);           // 1 MB
  float4*   s        = (float4*)nxt((size_t)NPTS * 16);          // 1 MB
  float4*   q        = (float4*)nxt((size_t)NPTS * 16);          // 1 MB
  unsigned* wl       = (unsigned*)nxt((size_t)NPTS * 4);         // 256 KB
  float*    wlBest   = (float*)nxt((size_t)NPTS * 4);            // 256 KB

  hipMemsetAsync(counts1, 0, (size_t)2 * NC * 4 + 1024, stream);

  count_kernel<<<2 * NPTS / BLOCK, BLOCK, 0, stream>>>(pc0, pc1, counts0, counts1);
  scan_partial_kernel<<<dim3(SB, 2), 1024, 0, stream>>>(counts0, counts1, partials);
  scan_mid_kernel<<<1, 256, 0, stream>>>(partials);
  scan_final_kernel<<<dim3(SB, 2), 1024, 0, stream>>>(counts0, cur0,
                                                      counts1, cur1, partials);
  scatter_kernel<<<2 * NPTS / BLOCK, BLOCK, 0, stream>>>(
      pc0, pc1, cur0, cur1, q, s);
  query_kernel<<<2 * NPTS / BLOCK, BLOCK, 0, stream>>>(q, cur1, s, wl, wlBest,
                                                       pendCnt, bkt);
  pending_kernel<<<PBLOCKS, BLOCK, 0, stream>>>(q, cur1, s, wl, wlBest,
                                                pendCnt, bkt, done, out);
}